// Round 10
// baseline (125.799 us; speedup 1.0000x reference)
//
#include <hip/hip_runtime.h>
#include <hip/hip_bf16.h>

typedef unsigned short ushort_t;
typedef __attribute__((ext_vector_type(4))) float f32x4;
typedef __attribute__((ext_vector_type(8))) short bf16x8;
typedef __attribute__((ext_vector_type(8))) unsigned short u16x8;

#define M_DIM 2048
#define N_DIM 4096
#define K_DIM 4096
#define BM 256
#define BN 128
#define BK 64
#define NT (K_DIM / BK)   // 64 K-tiles

#define MFMA16(a, b, c) __builtin_amdgcn_mfma_f32_16x16x32_bf16((a), (b), (c), 0, 0, 0)

// ---------- helpers ----------
__device__ __forceinline__ unsigned short f2bf(float f) {
  unsigned int u = __float_as_uint(f);
  u += 0x7FFFu + ((u >> 16) & 1u);   // round-to-nearest-even
  return (unsigned short)(u >> 16);
}

__device__ __forceinline__ void async16(void* l, const void* g) {
  __builtin_amdgcn_global_load_lds(
      (const __attribute__((address_space(1))) void*)g,
      (__attribute__((address_space(3))) void*)l,
      16, 0, 0);
}

// ---------- kernel 1: fused [x fp32->bf16] + [W build, c1 staged in LDS] ----------
// (unchanged from round 5: ~26us)
__global__ void k_prep(const float* __restrict__ x, ushort_t* __restrict__ o,
                       const float* __restrict__ c0, const float* __restrict__ c1,
                       const float* __restrict__ c2, ushort_t* __restrict__ wt) {
  __shared__ float sc1[16 * 260];
  const int bid = blockIdx.x;
  const int tid = threadIdx.x;
  if (bid < 2048) {
    const int n4 = (M_DIM * K_DIM) / 4;
    for (int i = bid * 256 + tid; i < n4; i += 2048 * 256) {
      float4 v = ((const float4*)x)[i];
      ushort4 r;
      r.x = f2bf(v.x); r.y = f2bf(v.y); r.z = f2bf(v.z); r.w = f2bf(v.w);
      ((ushort4*)o)[i] = r;
    }
  } else {
    const int out = bid - 2048;
    const int o3 = out & 15;
    const int o2 = (out >> 4) & 15;
    const int o1 = out >> 8;
    {
      const int q  = tid >> 4;
      const int i2 = tid & 15;
      const float* src = c1 + q * 4096 + i2 * 256 + o2 * 16;
      float* dst = &sc1[i2 * 260 + q * 16];
      #pragma unroll
      for (int rr = 0; rr < 4; ++rr)
        *(float4*)(dst + rr * 4) = *(const float4*)(src + rr * 4);
    }
    __syncthreads();

    const int i2 = tid & 15;
    const int i1 = tid >> 4;
    float4 a4[4];
    {
      const float* c0p = c0 + (i1 * 16 + o1) * 16;
      #pragma unroll
      for (int rr = 0; rr < 4; ++rr) a4[rr] = *(const float4*)(c0p + rr * 4);
    }
    float t01r[16];
    #pragma unroll
    for (int r = 0; r < 16; ++r) t01r[r] = 0.f;
    #pragma unroll
    for (int q = 0; q < 16; ++q) {
      const float a = a4[q >> 2][q & 3];
      const float* sp = &sc1[i2 * 260 + q * 16];
      #pragma unroll
      for (int rr = 0; rr < 4; ++rr) {
        float4 v = *(const float4*)(sp + rr * 4);
        t01r[rr * 4 + 0] += a * v.x;
        t01r[rr * 4 + 1] += a * v.y;
        t01r[rr * 4 + 2] += a * v.z;
        t01r[rr * 4 + 3] += a * v.w;
      }
    }
    u16x8 lo, hi;
    #pragma unroll
    for (int i3 = 0; i3 < 16; ++i3) {
      const float* c2p = c2 + i3 * 16 + o3;
      float s = 0.f;
      #pragma unroll
      for (int rr = 0; rr < 16; ++rr) s += t01r[rr] * c2p[rr * 256];
      ushort_t v = f2bf(s);
      if (i3 < 8) lo[i3] = v; else hi[i3 - 8] = v;
    }
    u16x8* dst = (u16x8*)(wt + ((size_t)out << 12) + (i1 << 8) + (i2 << 4));
    dst[0] = lo;
    dst[1] = hi;
  }
}

// ---------- kernel 2: GEMM C[M][N] = A[M][K] * Wt[N][K]^T + bias ----------
// R5 geometry (BM=256 BN=128 BK=64, 8 waves 64x64, 3-slot swizzled LDS,
// counted vmcnt(6)) with mid-phase barriers REMOVED: one barrier + one vmcnt
// per K-tile; waves free-run inside the tile so ds_read and MFMA pipes overlap
// via wave drift (m114 mechanism) instead of lockstep-serializing.
__global__ __launch_bounds__(512, 1) void k_gemm(
    const ushort_t* __restrict__ A,
    const ushort_t* __restrict__ Bt,
    const float* __restrict__ bias,
    float* __restrict__ C)
{
  __shared__ ushort_t lA[3][BM * BK];   // 3 x 32KB
  __shared__ ushort_t lB[3][BN * BK];   // 3 x 16KB  (total 144KB)

  const int tid  = threadIdx.x;
  const int lane = tid & 63;
  const int wid  = tid >> 6;     // 0..7
  const int wm   = wid >> 1;     // 0..3  (M quadrant, 64 rows)
  const int wn   = wid & 1;      // 0..1  (N half, 64 cols)
  const int fr   = lane & 15;
  const int fg   = lane >> 4;    // 0..3

  // XCD swizzle: 256 wgs; bm = bid&7 -> each XCD owns one A-panel (2MB, L2-fit)
  const int bid = blockIdx.x;
  const int bm  = bid & 7;       // 0..7
  const int bn  = bid >> 3;      // 0..31

  // ---- staging (linear LDS dest + inverse-swizzled global source) ----
  const int srow = tid >> 3;                               // 0..63
  const int scol = ((tid & 7) ^ (srow & 7)) << 3;          // swizzled source col (elems)
  const ushort_t* aSt = A  + (size_t)(bm * BM + srow) * K_DIM + scol;
  const ushort_t* bSt = Bt + (size_t)(bn * BN + srow) * K_DIM + scol;
  const int dE = tid * 8;                                  // linear dest (elems)

#define STAGE_A(kt, s, r_) async16(&lA[s][(r_) * 4096 + dE], \
                                   aSt + (size_t)(kt) * BK + (size_t)(r_) * 64 * K_DIM)
#define STAGE_B(kt, s, r_) async16(&lB[s][(r_) * 4096 + dE], \
                                   bSt + (size_t)(kt) * BK + (size_t)(r_) * 64 * K_DIM)

  // ---- fragment read addressing (swizzle applied on read; verified 0 conflicts) ----
  const int arowb = wm * 64 + fr;                // + m*16
  const int browb = wn * 64 + fr;                // + n*16
  const int c0 = ( fg      ^ (fr & 7)) << 3;     // kk=0 col (elems)
  const int c1 = ((fg + 4) ^ (fr & 7)) << 3;     // kk=1

  f32x4 acc[4][4];
  #pragma unroll
  for (int m = 0; m < 4; ++m)
    #pragma unroll
    for (int n = 0; n < 4; ++n)
      acc[m][n] = (f32x4){0.f, 0.f, 0.f, 0.f};

  // prologue: stage tiles 0,1 (6 chunks each)
  #pragma unroll
  for (int r_ = 0; r_ < 4; ++r_) STAGE_A(0, 0, r_);
  #pragma unroll
  for (int r_ = 0; r_ < 2; ++r_) STAGE_B(0, 0, r_);
  #pragma unroll
  for (int r_ = 0; r_ < 4; ++r_) STAGE_A(1, 1, r_);
  #pragma unroll
  for (int r_ = 0; r_ < 2; ++r_) STAGE_B(1, 1, r_);

  asm volatile("s_waitcnt vmcnt(6)" ::: "memory");   // tile 0 resident (per-wave)
  __builtin_amdgcn_s_barrier();                      // ... for ALL waves

  int sc = 0, ss = 2;
  for (int t = 0; t < NT; ++t) {
    const bool pre = (t + 2 < NT);
    const ushort_t* pA = &lA[sc][0];
    const ushort_t* pB = &lB[sc][0];

    // ---- issue all 6 stage chunks for tile t+2 up front (DMA queues) ----
    if (pre) {
      STAGE_A(t + 2, ss, 0); STAGE_A(t + 2, ss, 1);
      STAGE_A(t + 2, ss, 2); STAGE_A(t + 2, ss, 3);
      STAGE_B(t + 2, ss, 0); STAGE_B(t + 2, ss, 1);
    }

    // ---- kk=0: reads + 16 MFMA (no barrier; waves free-run) ----
    {
      bf16x8 af[4], bf[4];
      #pragma unroll
      for (int m = 0; m < 4; ++m) af[m] = *(const bf16x8*)(pA + (arowb + m * 16) * 64 + c0);
      #pragma unroll
      for (int n = 0; n < 4; ++n) bf[n] = *(const bf16x8*)(pB + (browb + n * 16) * 64 + c0);
      __builtin_amdgcn_s_setprio(1);
      #pragma unroll
      for (int m = 0; m < 4; ++m)
        #pragma unroll
        for (int n = 0; n < 4; ++n)
          acc[m][n] = MFMA16(af[m], bf[n], acc[m][n]);
      __builtin_amdgcn_s_setprio(0);
    }

    // ---- kk=1: reads + 16 MFMA ----
    {
      bf16x8 af[4], bf[4];
      #pragma unroll
      for (int m = 0; m < 4; ++m) af[m] = *(const bf16x8*)(pA + (arowb + m * 16) * 64 + c1);
      #pragma unroll
      for (int n = 0; n < 4; ++n) bf[n] = *(const bf16x8*)(pB + (browb + n * 16) * 64 + c1);
      __builtin_amdgcn_s_setprio(1);
      #pragma unroll
      for (int m = 0; m < 4; ++m)
        #pragma unroll
        for (int n = 0; n < 4; ++n)
          acc[m][n] = MFMA16(af[m], bf[n], acc[m][n]);
      __builtin_amdgcn_s_setprio(0);
    }

    // ---- tile end: drain stage(t+1) (leave newest 6 = stage(t+2) in flight) ----
    if (t + 2 < NT)      asm volatile("s_waitcnt vmcnt(6)" ::: "memory");
    else                 asm volatile("s_waitcnt vmcnt(0)" ::: "memory");
    __builtin_amdgcn_s_barrier();   // slot-rotation safety + stage(t+1) visible

    sc = (sc == 2) ? 0 : sc + 1;
    ss = (ss == 2) ? 0 : ss + 1;
  }
#undef STAGE_A
#undef STAGE_B

  // epilogue: C/D layout col = lane&15, row = (lane>>4)*4 + reg
  const size_t row0 = (size_t)bm * BM + wm * 64;
  const int col0 = bn * BN + wn * 64;
  #pragma unroll
  for (int n = 0; n < 4; ++n) {
    const int col = col0 + n * 16 + fr;
    const float bv = bias[col];
    #pragma unroll
    for (int m = 0; m < 4; ++m) {
      const size_t r0 = row0 + m * 16 + fg * 4;
      #pragma unroll
      for (int r = 0; r < 4; ++r)
        C[(r0 + r) * N_DIM + col] = acc[m][n][r] + bv;
    }
  }
}

// ---------- launch ----------
extern "C" void kernel_launch(void* const* d_in, const int* in_sizes, int n_in,
                              void* d_out, int out_size, void* d_ws, size_t ws_size,
                              hipStream_t stream) {
  const float* x    = (const float*)d_in[0];
  const float* c0   = (const float*)d_in[1];
  const float* c1   = (const float*)d_in[2];
  const float* c2   = (const float*)d_in[3];
  const float* bias = (const float*)d_in[4];
  float* out = (float*)d_out;

  // workspace layout: Abf 16MB | Wt 32MB => 48MB needed
  const size_t NEED = (size_t)48 * 1024 * 1024;
  if (ws_size < NEED) return;

  char* ws = (char*)d_ws;
  ushort_t* Abf = (ushort_t*)ws;
  ushort_t* Wt  = (ushort_t*)(ws + (size_t)16 * 1024 * 1024);

  k_prep <<<6144, 256, 0, stream>>>(x, Abf, c0, c1, c2, Wt);
  k_gemm <<<256, 512, 0, stream>>>(Abf, Wt, bias, out);
}

// Round 11
// 123.194 us; speedup vs baseline: 1.0211x; 1.0211x over previous
//
#include <hip/hip_runtime.h>
#include <hip/hip_bf16.h>

typedef unsigned short ushort_t;
typedef __attribute__((ext_vector_type(4))) float f32x4;
typedef __attribute__((ext_vector_type(8))) short bf16x8;
typedef __attribute__((ext_vector_type(8))) unsigned short u16x8;

#define M_DIM 2048
#define N_DIM 4096
#define K_DIM 4096
#define BK 32
#define NT 64            // K-tiles per kz half (2048 / 32)

#define MFMA16(a, b, c) __builtin_amdgcn_mfma_f32_16x16x32_bf16((a), (b), (c), 0, 0, 0)

// ---------- helpers ----------
__device__ __forceinline__ unsigned short f2bf(float f) {
  unsigned int u = __float_as_uint(f);
  u += 0x7FFFu + ((u >> 16) & 1u);   // round-to-nearest-even
  return (unsigned short)(u >> 16);
}
__device__ __forceinline__ float bf2f(unsigned short u) {
  return __uint_as_float(((unsigned int)u) << 16);
}

__device__ __forceinline__ void async16(void* l, const void* g) {
  __builtin_amdgcn_global_load_lds(
      (const __attribute__((address_space(1))) void*)g,
      (__attribute__((address_space(3))) void*)l,
      16, 0, 0);
}

// ---------- kernel 1: fused [x fp32->bf16] + [W build, c1 staged in LDS] ----------
// (unchanged, verified, ~26us)
__global__ void k_prep(const float* __restrict__ x, ushort_t* __restrict__ o,
                       const float* __restrict__ c0, const float* __restrict__ c1,
                       const float* __restrict__ c2, ushort_t* __restrict__ wt) {
  __shared__ float sc1[16 * 260];
  const int bid = blockIdx.x;
  const int tid = threadIdx.x;
  if (bid < 2048) {
    const int n4 = (M_DIM * K_DIM) / 4;
    for (int i = bid * 256 + tid; i < n4; i += 2048 * 256) {
      float4 v = ((const float4*)x)[i];
      ushort4 r;
      r.x = f2bf(v.x); r.y = f2bf(v.y); r.z = f2bf(v.z); r.w = f2bf(v.w);
      ((ushort4*)o)[i] = r;
    }
  } else {
    const int out = bid - 2048;
    const int o3 = out & 15;
    const int o2 = (out >> 4) & 15;
    const int o1 = out >> 8;
    {
      const int q  = tid >> 4;
      const int i2 = tid & 15;
      const float* src = c1 + q * 4096 + i2 * 256 + o2 * 16;
      float* dst = &sc1[i2 * 260 + q * 16];
      #pragma unroll
      for (int rr = 0; rr < 4; ++rr)
        *(float4*)(dst + rr * 4) = *(const float4*)(src + rr * 4);
    }
    __syncthreads();

    const int i2 = tid & 15;
    const int i1 = tid >> 4;
    float4 a4[4];
    {
      const float* c0p = c0 + (i1 * 16 + o1) * 16;
      #pragma unroll
      for (int rr = 0; rr < 4; ++rr) a4[rr] = *(const float4*)(c0p + rr * 4);
    }
    float t01r[16];
    #pragma unroll
    for (int r = 0; r < 16; ++r) t01r[r] = 0.f;
    #pragma unroll
    for (int q = 0; q < 16; ++q) {
      const float a = a4[q >> 2][q & 3];
      const float* sp = &sc1[i2 * 260 + q * 16];
      #pragma unroll
      for (int rr = 0; rr < 4; ++rr) {
        float4 v = *(const float4*)(sp + rr * 4);
        t01r[rr * 4 + 0] += a * v.x;
        t01r[rr * 4 + 1] += a * v.y;
        t01r[rr * 4 + 2] += a * v.z;
        t01r[rr * 4 + 3] += a * v.w;
      }
    }
    u16x8 lo, hi;
    #pragma unroll
    for (int i3 = 0; i3 < 16; ++i3) {
      const float* c2p = c2 + i3 * 16 + o3;
      float s = 0.f;
      #pragma unroll
      for (int rr = 0; rr < 16; ++rr) s += t01r[rr] * c2p[rr * 256];
      ushort_t v = f2bf(s);
      if (i3 < 8) lo[i3] = v; else hi[i3 - 8] = v;
    }
    u16x8* dst = (u16x8*)(wt + ((size_t)out << 12) + (i1 << 8) + (i2 << 4));
    dst[0] = lo;
    dst[1] = hi;
  }
}

// ---------- kernel 2: split-K 256^2 GEMM, m201-faithful phase discipline ------
// BK=32, 4-slot LDS ring (128KB), stage tile t+3 during tile t, counted
// vmcnt(8) once per tile, 2 phases/tile of {reads | 2 gloads | barrier |
// setprio | 16 MFMA | setprio | barrier}. No swizzle needed: 64B LDS rows
// give natural 2-way (free) bank spread for 16-lane frag reads.
__global__ __launch_bounds__(512, 1) void k_gemm_sk(
    const ushort_t* __restrict__ A,
    const ushort_t* __restrict__ Bt,
    float* __restrict__ C0,
    ushort_t* __restrict__ P1b)
{
  __shared__ ushort_t lA[4][256 * BK];   // 4 x 16KB
  __shared__ ushort_t lB[4][256 * BK];   // 4 x 16KB  (total 128KB)

  const int tid  = threadIdx.x;
  const int lane = tid & 63;
  const int wid  = tid >> 6;     // 0..7
  const int wm   = wid >> 2;     // 0..1  (M half, 128 rows)
  const int wn   = wid & 3;      // 0..3  (N quarter, 64 cols)
  const int fr   = lane & 15;
  const int fg   = lane >> 4;    // 0..3

  // bm = bid&7 -> each XCD owns one 2MB A-panel (L2-fit); bn/kz from the rest
  const int bid = blockIdx.x;
  const int bm  = bid & 7;
  const int rst = bid >> 3;
  const int bn  = rst & 15;
  const int kz  = rst >> 4;

  // ---- staging addressing: tile = 256 rows x 32 cols = 1024 16B-chunks;
  //      thread tid, load l: chunk c = tid + 512*l -> row c>>2, quarter tid&3.
  const int sRow = tid >> 2;            // 0..127 (l=0); +128 for l=1
  const int sQ   = tid & 3;
  const ushort_t* aSrc = A  + (size_t)(bm * 256 + sRow) * K_DIM + kz * 2048 + sQ * 8;
  const ushort_t* bSrc = Bt + (size_t)(bn * 256 + sRow) * K_DIM + kz * 2048 + sQ * 8;
  const int dE = tid * 8;               // LDS dest elems (l=0); +4096 for l=1

#define SA(kt, s, l) async16(&lA[s][dE + 4096 * (l)], \
                             aSrc + (size_t)(l) * 128 * K_DIM + (size_t)(kt) * BK)
#define SB(kt, s, l) async16(&lB[s][dE + 4096 * (l)], \
                             bSrc + (size_t)(l) * 128 * K_DIM + (size_t)(kt) * BK)

  // ---- fragment read addressing (linear; natural 2-way bank spread) ----
  const int aR0 = (wm * 128 + fr) * BK + fg * 8;   // + m*16*BK, + 64*BK for mh1
  const int bR0 = (wn * 64  + fr) * BK + fg * 8;   // + n*16*BK

  f32x4 acc[8][4];
  #pragma unroll
  for (int m = 0; m < 8; ++m)
    #pragma unroll
    for (int n = 0; n < 4; ++n)
      acc[m][n] = (f32x4){0.f, 0.f, 0.f, 0.f};

  // prologue: stage tiles 0,1,2 into slots 0,1,2 (12 loads)
  SA(0, 0, 0); SA(0, 0, 1); SB(0, 0, 0); SB(0, 0, 1);
  SA(1, 1, 0); SA(1, 1, 1); SB(1, 1, 0); SB(1, 1, 1);
  SA(2, 2, 0); SA(2, 2, 1); SB(2, 2, 0); SB(2, 2, 1);
  asm volatile("s_waitcnt vmcnt(8)" ::: "memory");   // tile 0 resident
  __builtin_amdgcn_s_barrier();

  for (int t = 0; t < NT; ++t) {
    const int s  = t & 3;
    const int sp = (t + 3) & 3;
    const bool pre = (t + 3 < NT);
    const ushort_t* pA = &lA[s][0];
    const ushort_t* pB = &lB[s][0];

    bf16x8 bf[4], af[4];

    // ===== phase 0: B all-n + A mh0; stage A(t+3); MFMA mh0 (16) =====
    #pragma unroll
    for (int n = 0; n < 4; ++n) bf[n] = *(const bf16x8*)(pB + bR0 + n * 16 * BK);
    #pragma unroll
    for (int m = 0; m < 4; ++m) af[m] = *(const bf16x8*)(pA + aR0 + m * 16 * BK);
    if (pre) { SA(t + 3, sp, 0); SA(t + 3, sp, 1); }
    __builtin_amdgcn_s_barrier();
    __builtin_amdgcn_s_setprio(1);
    #pragma unroll
    for (int m = 0; m < 4; ++m)
      #pragma unroll
      for (int n = 0; n < 4; ++n)
        acc[m][n] = MFMA16(af[m], bf[n], acc[m][n]);
    __builtin_amdgcn_s_setprio(0);
    __builtin_amdgcn_s_barrier();

    // ===== phase 1: A mh1; stage B(t+3); MFMA mh1 (16); vmcnt; barrier =====
    #pragma unroll
    for (int m = 0; m < 4; ++m) af[m] = *(const bf16x8*)(pA + aR0 + (64 + m * 16) * BK);
    if (pre) { SB(t + 3, sp, 0); SB(t + 3, sp, 1); }
    __builtin_amdgcn_s_barrier();
    __builtin_amdgcn_s_setprio(1);
    #pragma unroll
    for (int m = 0; m < 4; ++m)
      #pragma unroll
      for (int n = 0; n < 4; ++n)
        acc[4 + m][n] = MFMA16(af[m], bf[n], acc[4 + m][n]);
    __builtin_amdgcn_s_setprio(0);
    // drain so tile t+1 is resident; loads waited on are >= 4 phases old
    if (t + 3 < NT)      asm volatile("s_waitcnt vmcnt(8)" ::: "memory");
    else if (t + 2 < NT) asm volatile("s_waitcnt vmcnt(4)" ::: "memory");
    else if (t + 1 < NT) asm volatile("s_waitcnt vmcnt(0)" ::: "memory");
    __builtin_amdgcn_s_barrier();
  }
#undef SA
#undef SB

  // epilogue: C/D layout col = lane&15, row = (lane>>4)*4 + reg  (R9-verified)
  const size_t row0 = (size_t)bm * 256 + wm * 128;
  const int col0 = bn * 256 + wn * 64;
  if (kz == 0) {
    #pragma unroll
    for (int n = 0; n < 4; ++n) {
      const int col = col0 + n * 16 + fr;
      #pragma unroll
      for (int m = 0; m < 8; ++m) {
        const size_t r0 = row0 + m * 16 + fg * 4;
        #pragma unroll
        for (int r = 0; r < 4; ++r)
          C0[(r0 + r) * N_DIM + col] = acc[m][n][r];
      }
    }
  } else {
    #pragma unroll
    for (int n = 0; n < 4; ++n) {
      const int col = col0 + n * 16 + fr;
      #pragma unroll
      for (int m = 0; m < 8; ++m) {
        const size_t r0 = row0 + m * 16 + fg * 4;
        #pragma unroll
        for (int r = 0; r < 4; ++r)
          P1b[(r0 + r) * N_DIM + col] = f2bf(acc[m][n][r]);
      }
    }
  }
}

// ---------- kernel 3: out = out(kz0 f32) + bf16(kz1 partial) + bias ----------
// (unchanged, R9-verified)
__global__ void k_reduce(float* __restrict__ out, const ushort_t* __restrict__ p1,
                         const float* __restrict__ bias) {
  const int idx = blockIdx.x * 256 + threadIdx.x;   // 1M threads, 8 elems each
  const int base = idx * 8;
  const int col = base & (N_DIM - 1);
  float4 o0 = *(float4*)(out + base);
  float4 o1 = *(float4*)(out + base + 4);
  u16x8 p = *(const u16x8*)(p1 + base);
  float4 b0 = *(const float4*)(bias + col);
  float4 b1 = *(const float4*)(bias + col + 4);
  o0.x += bf2f(p[0]) + b0.x;  o0.y += bf2f(p[1]) + b0.y;
  o0.z += bf2f(p[2]) + b0.z;  o0.w += bf2f(p[3]) + b0.w;
  o1.x += bf2f(p[4]) + b1.x;  o1.y += bf2f(p[5]) + b1.y;
  o1.z += bf2f(p[6]) + b1.z;  o1.w += bf2f(p[7]) + b1.w;
  *(float4*)(out + base)     = o0;
  *(float4*)(out + base + 4) = o1;
}

// ---------- launch ----------
extern "C" void kernel_launch(void* const* d_in, const int* in_sizes, int n_in,
                              void* d_out, int out_size, void* d_ws, size_t ws_size,
                              hipStream_t stream) {
  const float* x    = (const float*)d_in[0];
  const float* c0   = (const float*)d_in[1];
  const float* c1   = (const float*)d_in[2];
  const float* c2   = (const float*)d_in[3];
  const float* bias = (const float*)d_in[4];
  float* out = (float*)d_out;

  const size_t MB = 1024 * 1024;
  if (ws_size < 64 * MB) return;   // Abf 16 | Wt 32 | P1b 16 (verified available in R9)

  char* ws = (char*)d_ws;
  ushort_t* Abf = (ushort_t*)ws;
  ushort_t* Wt  = (ushort_t*)(ws + 16 * MB);
  ushort_t* P1b = (ushort_t*)(ws + 48 * MB);

  k_prep   <<<6144, 256, 0, stream>>>(x, Abf, c0, c1, c2, Wt);
  k_gemm_sk<<<256, 512, 0, stream>>>(Abf, Wt, out, P1b);
  k_reduce <<<4096, 256, 0, stream>>>(out, P1b, bias);
}

// Round 12
// 121.920 us; speedup vs baseline: 1.0318x; 1.0105x over previous
//
#include <hip/hip_runtime.h>
#include <hip/hip_bf16.h>

typedef unsigned short ushort_t;
typedef __attribute__((ext_vector_type(4))) float f32x4;
typedef __attribute__((ext_vector_type(8))) short bf16x8;
typedef __attribute__((ext_vector_type(8))) unsigned short u16x8;

#define M_DIM 2048
#define N_DIM 4096
#define K_DIM 4096
#define BK 32
#define NT 64            // K-tiles per kz half (2048 / 32)

#define MFMA16(a, b, c) __builtin_amdgcn_mfma_f32_16x16x32_bf16((a), (b), (c), 0, 0, 0)

// ---------- helpers ----------
__device__ __forceinline__ unsigned short f2bf(float f) {
  unsigned int u = __float_as_uint(f);
  u += 0x7FFFu + ((u >> 16) & 1u);   // round-to-nearest-even
  return (unsigned short)(u >> 16);
}
__device__ __forceinline__ float bf2f(unsigned short u) {
  return __uint_as_float(((unsigned int)u) << 16);
}

__device__ __forceinline__ void async16(void* l, const void* g) {
  __builtin_amdgcn_global_load_lds(
      (const __attribute__((address_space(1))) void*)g,
      (__attribute__((address_space(3))) void*)l,
      16, 0, 0);
}

// ---------- kernel 1: fused [x fp32->bf16] + [W build, c1 staged in LDS] ----------
// (unchanged, verified, ~26us)
__global__ void k_prep(const float* __restrict__ x, ushort_t* __restrict__ o,
                       const float* __restrict__ c0, const float* __restrict__ c1,
                       const float* __restrict__ c2, ushort_t* __restrict__ wt) {
  __shared__ float sc1[16 * 260];
  const int bid = blockIdx.x;
  const int tid = threadIdx.x;
  if (bid < 2048) {
    const int n4 = (M_DIM * K_DIM) / 4;
    for (int i = bid * 256 + tid; i < n4; i += 2048 * 256) {
      float4 v = ((const float4*)x)[i];
      ushort4 r;
      r.x = f2bf(v.x); r.y = f2bf(v.y); r.z = f2bf(v.z); r.w = f2bf(v.w);
      ((ushort4*)o)[i] = r;
    }
  } else {
    const int out = bid - 2048;
    const int o3 = out & 15;
    const int o2 = (out >> 4) & 15;
    const int o1 = out >> 8;
    {
      const int q  = tid >> 4;
      const int i2 = tid & 15;
      const float* src = c1 + q * 4096 + i2 * 256 + o2 * 16;
      float* dst = &sc1[i2 * 260 + q * 16];
      #pragma unroll
      for (int rr = 0; rr < 4; ++rr)
        *(float4*)(dst + rr * 4) = *(const float4*)(src + rr * 4);
    }
    __syncthreads();

    const int i2 = tid & 15;
    const int i1 = tid >> 4;
    float4 a4[4];
    {
      const float* c0p = c0 + (i1 * 16 + o1) * 16;
      #pragma unroll
      for (int rr = 0; rr < 4; ++rr) a4[rr] = *(const float4*)(c0p + rr * 4);
    }
    float t01r[16];
    #pragma unroll
    for (int r = 0; r < 16; ++r) t01r[r] = 0.f;
    #pragma unroll
    for (int q = 0; q < 16; ++q) {
      const float a = a4[q >> 2][q & 3];
      const float* sp = &sc1[i2 * 260 + q * 16];
      #pragma unroll
      for (int rr = 0; rr < 4; ++rr) {
        float4 v = *(const float4*)(sp + rr * 4);
        t01r[rr * 4 + 0] += a * v.x;
        t01r[rr * 4 + 1] += a * v.y;
        t01r[rr * 4 + 2] += a * v.z;
        t01r[rr * 4 + 3] += a * v.w;
      }
    }
    u16x8 lo, hi;
    #pragma unroll
    for (int i3 = 0; i3 < 16; ++i3) {
      const float* c2p = c2 + i3 * 16 + o3;
      float s = 0.f;
      #pragma unroll
      for (int rr = 0; rr < 16; ++rr) s += t01r[rr] * c2p[rr * 256];
      ushort_t v = f2bf(s);
      if (i3 < 8) lo[i3] = v; else hi[i3 - 8] = v;
    }
    u16x8* dst = (u16x8*)(wt + ((size_t)out << 12) + (i1 << 8) + (i2 << 4));
    dst[0] = lo;
    dst[1] = hi;
  }
}

// ---------- kernel 2: split-K 256^2 GEMM (R11 schedule + both-sides swizzle) --
// BK=32, 4-slot LDS ring (128KB), stage tile t+3 during tile t, counted
// vmcnt(8) once per tile (drained loads are ~2 tiles old), 2 phases/tile.
// Bank fix: col16 = fg ^ ((fr>>1)&3) -> quarter-wave hits all 8 bank groups
// exactly 2x (free). Linear DMA dest + inverse-permuted global source col.
__global__ __launch_bounds__(512, 1) void k_gemm_sk(
    const ushort_t* __restrict__ A,
    const ushort_t* __restrict__ Bt,
    float* __restrict__ C0,
    ushort_t* __restrict__ P1b)
{
  __shared__ ushort_t lA[4][256 * BK];   // 4 x 16KB
  __shared__ ushort_t lB[4][256 * BK];   // 4 x 16KB  (total 128KB)

  const int tid  = threadIdx.x;
  const int lane = tid & 63;
  const int wid  = tid >> 6;     // 0..7
  const int wm   = wid >> 2;     // 0..1  (M half, 128 rows)
  const int wn   = wid & 3;      // 0..3  (N quarter, 64 cols)
  const int fr   = lane & 15;
  const int fg   = lane >> 4;    // 0..3

  // bm = bid&7 -> each XCD owns one 2MB A-panel (L2-fit); bn/kz from the rest
  const int bid = blockIdx.x;
  const int bm  = bid & 7;
  const int rst = bid >> 3;
  const int bn  = rst & 15;
  const int kz  = rst >> 4;

  // ---- staging: tile = 256 rows x 2 col16-quarters... chunk c = tid + 512*l
  //      -> LDS row c>>2, col16 q = tid&3 (linear dest). Global source col is
  //      inverse-swizzled: colg = q ^ ((row>>1)&3)  (row>>1 invariant to +128).
  const int sRow = tid >> 2;                                    // 0..127 (l=0)
  const int sCol = (((tid & 3) ^ ((sRow >> 1) & 3))) << 3;      // elems
  const ushort_t* aSrc = A  + (size_t)(bm * 256 + sRow) * K_DIM + kz * 2048 + sCol;
  const ushort_t* bSrc = Bt + (size_t)(bn * 256 + sRow) * K_DIM + kz * 2048 + sCol;
  const int dE = tid * 8;               // LDS dest elems (l=0); +4096 for l=1

#define SA(kt, s, l) async16(&lA[s][dE + 4096 * (l)], \
                             aSrc + (size_t)(l) * 128 * K_DIM + (size_t)(kt) * BK)
#define SB(kt, s, l) async16(&lB[s][dE + 4096 * (l)], \
                             bSrc + (size_t)(l) * 128 * K_DIM + (size_t)(kt) * BK)

  // ---- fragment read addressing (same swizzle on read; 2-way = free) ----
  const int cSwz = (fg ^ ((fr >> 1) & 3)) << 3;                 // elems
  const int aR0 = (wm * 128 + fr) * BK + cSwz;   // + m*16*BK
  const int bR0 = (wn * 64  + fr) * BK + cSwz;   // + n*16*BK

  f32x4 acc[8][4];
  #pragma unroll
  for (int m = 0; m < 8; ++m)
    #pragma unroll
    for (int n = 0; n < 4; ++n)
      acc[m][n] = (f32x4){0.f, 0.f, 0.f, 0.f};

  // prologue: stage tiles 0,1,2 into slots 0,1,2 (12 loads)
  SA(0, 0, 0); SA(0, 0, 1); SB(0, 0, 0); SB(0, 0, 1);
  SA(1, 1, 0); SA(1, 1, 1); SB(1, 1, 0); SB(1, 1, 1);
  SA(2, 2, 0); SA(2, 2, 1); SB(2, 2, 0); SB(2, 2, 1);
  asm volatile("s_waitcnt vmcnt(8)" ::: "memory");   // tile 0 resident
  __builtin_amdgcn_s_barrier();

  for (int t = 0; t < NT; ++t) {
    const int s  = t & 3;
    const int sp = (t + 3) & 3;
    const bool pre = (t + 3 < NT);
    const ushort_t* pA = &lA[s][0];
    const ushort_t* pB = &lB[s][0];

    bf16x8 bf[4], af[4];

    // ===== phase 0: B all-n + A mh0; stage A(t+3); MFMA mh0 (16) =====
    #pragma unroll
    for (int n = 0; n < 4; ++n) bf[n] = *(const bf16x8*)(pB + bR0 + n * 16 * BK);
    #pragma unroll
    for (int m = 0; m < 4; ++m) af[m] = *(const bf16x8*)(pA + aR0 + m * 16 * BK);
    if (pre) { SA(t + 3, sp, 0); SA(t + 3, sp, 1); }
    __builtin_amdgcn_s_barrier();
    __builtin_amdgcn_s_setprio(1);
    #pragma unroll
    for (int m = 0; m < 4; ++m)
      #pragma unroll
      for (int n = 0; n < 4; ++n)
        acc[m][n] = MFMA16(af[m], bf[n], acc[m][n]);
    __builtin_amdgcn_s_setprio(0);
    __builtin_amdgcn_s_barrier();

    // ===== phase 1: A mh1; stage B(t+3); MFMA mh1 (16); vmcnt; barrier =====
    #pragma unroll
    for (int m = 0; m < 4; ++m) af[m] = *(const bf16x8*)(pA + aR0 + (64 + m * 16) * BK);
    if (pre) { SB(t + 3, sp, 0); SB(t + 3, sp, 1); }
    __builtin_amdgcn_s_barrier();
    __builtin_amdgcn_s_setprio(1);
    #pragma unroll
    for (int m = 0; m < 4; ++m)
      #pragma unroll
      for (int n = 0; n < 4; ++n)
        acc[4 + m][n] = MFMA16(af[m], bf[n], acc[4 + m][n]);
    __builtin_amdgcn_s_setprio(0);
    // drain so tile t+1 is resident; drained loads are ~2 tiles old
    if (t + 3 < NT)      asm volatile("s_waitcnt vmcnt(8)" ::: "memory");
    else if (t + 2 < NT) asm volatile("s_waitcnt vmcnt(4)" ::: "memory");
    else if (t + 1 < NT) asm volatile("s_waitcnt vmcnt(0)" ::: "memory");
    __builtin_amdgcn_s_barrier();
  }
#undef SA
#undef SB

  // epilogue: C/D layout col = lane&15, row = (lane>>4)*4 + reg  (verified)
  const size_t row0 = (size_t)bm * 256 + wm * 128;
  const int col0 = bn * 256 + wn * 64;
  if (kz == 0) {
    #pragma unroll
    for (int n = 0; n < 4; ++n) {
      const int col = col0 + n * 16 + fr;
      #pragma unroll
      for (int m = 0; m < 8; ++m) {
        const size_t r0 = row0 + m * 16 + fg * 4;
        #pragma unroll
        for (int r = 0; r < 4; ++r)
          C0[(r0 + r) * N_DIM + col] = acc[m][n][r];
      }
    }
  } else {
    #pragma unroll
    for (int n = 0; n < 4; ++n) {
      const int col = col0 + n * 16 + fr;
      #pragma unroll
      for (int m = 0; m < 8; ++m) {
        const size_t r0 = row0 + m * 16 + fg * 4;
        #pragma unroll
        for (int r = 0; r < 4; ++r)
          P1b[(r0 + r) * N_DIM + col] = f2bf(acc[m][n][r]);
      }
    }
  }
}

// ---------- kernel 3: out = out(kz0 f32) + bf16(kz1 partial) + bias ----------
// (unchanged, verified)
__global__ void k_reduce(float* __restrict__ out, const ushort_t* __restrict__ p1,
                         const float* __restrict__ bias) {
  const int idx = blockIdx.x * 256 + threadIdx.x;   // 1M threads, 8 elems each
  const int base = idx * 8;
  const int col = base & (N_DIM - 1);
  float4 o0 = *(float4*)(out + base);
  float4 o1 = *(float4*)(out + base + 4);
  u16x8 p = *(const u16x8*)(p1 + base);
  float4 b0 = *(const float4*)(bias + col);
  float4 b1 = *(const float4*)(bias + col + 4);
  o0.x += bf2f(p[0]) + b0.x;  o0.y += bf2f(p[1]) + b0.y;
  o0.z += bf2f(p[2]) + b0.z;  o0.w += bf2f(p[3]) + b0.w;
  o1.x += bf2f(p[4]) + b1.x;  o1.y += bf2f(p[5]) + b1.y;
  o1.z += bf2f(p[6]) + b1.z;  o1.w += bf2f(p[7]) + b1.w;
  *(float4*)(out + base)     = o0;
  *(float4*)(out + base + 4) = o1;
}

// ---------- launch ----------
extern "C" void kernel_launch(void* const* d_in, const int* in_sizes, int n_in,
                              void* d_out, int out_size, void* d_ws, size_t ws_size,
                              hipStream_t stream) {
  const float* x    = (const float*)d_in[0];
  const float* c0   = (const float*)d_in[1];
  const float* c1   = (const float*)d_in[2];
  const float* c2   = (const float*)d_in[3];
  const float* bias = (const float*)d_in[4];
  float* out = (float*)d_out;

  const size_t MB = 1024 * 1024;
  if (ws_size < 64 * MB) return;   // Abf 16 | Wt 32 | P1b 16

  char* ws = (char*)d_ws;
  ushort_t* Abf = (ushort_t*)ws;
  ushort_t* Wt  = (ushort_t*)(ws + 16 * MB);
  ushort_t* P1b = (ushort_t*)(ws + 48 * MB);

  k_prep   <<<6144, 256, 0, stream>>>(x, Abf, c0, c1, c2, Wt);
  k_gemm_sk<<<256, 512, 0, stream>>>(Abf, Wt, out, P1b);
  k_reduce <<<4096, 256, 0, stream>>>(out, P1b, bias);
}

// Round 13
// 106.674 us; speedup vs baseline: 1.1793x; 1.1429x over previous
//
#include <hip/hip_runtime.h>
#include <hip/hip_bf16.h>

typedef unsigned short ushort_t;
typedef __attribute__((ext_vector_type(4))) float f32x4;
typedef __attribute__((ext_vector_type(8))) short bf16x8;
typedef __attribute__((ext_vector_type(8))) unsigned short u16x8;

#define M_DIM 2048
#define N_DIM 4096
#define K_DIM 4096
#define BM 256
#define BN 128
#define BK 64
#define NT (K_DIM / BK)   // 64 K-tiles

#define MFMA16(a, b, c) __builtin_amdgcn_mfma_f32_16x16x32_bf16((a), (b), (c), 0, 0, 0)

// ---------- helpers ----------
__device__ __forceinline__ unsigned short f2bf(float f) {
  unsigned int u = __float_as_uint(f);
  u += 0x7FFFu + ((u >> 16) & 1u);   // round-to-nearest-even
  return (unsigned short)(u >> 16);
}

__device__ __forceinline__ void async16(void* l, const void* g) {
  __builtin_amdgcn_global_load_lds(
      (const __attribute__((address_space(1))) void*)g,
      (__attribute__((address_space(3))) void*)l,
      16, 0, 0);
}

// ---------- kernel 1: fused [x fp32->bf16] + [W build, c1 staged in LDS] ----------
// (verified R5, ~26us)
__global__ void k_prep(const float* __restrict__ x, ushort_t* __restrict__ o,
                       const float* __restrict__ c0, const float* __restrict__ c1,
                       const float* __restrict__ c2, ushort_t* __restrict__ wt) {
  __shared__ float sc1[16 * 260];   // [i2][q*16+r], stride 260 (bank-spread)
  const int bid = blockIdx.x;
  const int tid = threadIdx.x;
  if (bid < 2048) {
    const int n4 = (M_DIM * K_DIM) / 4;
    for (int i = bid * 256 + tid; i < n4; i += 2048 * 256) {
      float4 v = ((const float4*)x)[i];
      ushort4 r;
      r.x = f2bf(v.x); r.y = f2bf(v.y); r.z = f2bf(v.z); r.w = f2bf(v.w);
      ((ushort4*)o)[i] = r;
    }
  } else {
    const int out = bid - 2048;               // 0..4095 = (o1,o2,o3)
    const int o3 = out & 15;
    const int o2 = (out >> 4) & 15;
    const int o1 = out >> 8;

    {
      const int q  = tid >> 4;
      const int i2 = tid & 15;
      const float* src = c1 + q * 4096 + i2 * 256 + o2 * 16;
      float* dst = &sc1[i2 * 260 + q * 16];
      #pragma unroll
      for (int rr = 0; rr < 4; ++rr)
        *(float4*)(dst + rr * 4) = *(const float4*)(src + rr * 4);
    }
    __syncthreads();

    const int i2 = tid & 15;
    const int i1 = tid >> 4;

    float4 a4[4];
    {
      const float* c0p = c0 + (i1 * 16 + o1) * 16;
      #pragma unroll
      for (int rr = 0; rr < 4; ++rr) a4[rr] = *(const float4*)(c0p + rr * 4);
    }

    float t01r[16];
    #pragma unroll
    for (int r = 0; r < 16; ++r) t01r[r] = 0.f;
    #pragma unroll
    for (int q = 0; q < 16; ++q) {
      const float a = a4[q >> 2][q & 3];
      const float* sp = &sc1[i2 * 260 + q * 16];
      #pragma unroll
      for (int rr = 0; rr < 4; ++rr) {
        float4 v = *(const float4*)(sp + rr * 4);
        t01r[rr * 4 + 0] += a * v.x;
        t01r[rr * 4 + 1] += a * v.y;
        t01r[rr * 4 + 2] += a * v.z;
        t01r[rr * 4 + 3] += a * v.w;
      }
    }

    u16x8 lo, hi;
    #pragma unroll
    for (int i3 = 0; i3 < 16; ++i3) {
      const float* c2p = c2 + i3 * 16 + o3;
      float s = 0.f;
      #pragma unroll
      for (int rr = 0; rr < 16; ++rr) s += t01r[rr] * c2p[rr * 256];
      ushort_t v = f2bf(s);
      if (i3 < 8) lo[i3] = v; else hi[i3 - 8] = v;
    }
    u16x8* dst = (u16x8*)(wt + ((size_t)out << 12) + (i1 << 8) + (i2 << 4));
    dst[0] = lo;
    dst[1] = hi;
  }
}

// ---------- kernel 2: GEMM C[M][N] = A[M][K] * Wt[N][K]^T + bias ----------
// (verified R5 best: 80.1us, MfmaUtil 33-35%, 0 bank conflicts)
// BM=256 BN=128 BK=64, 512 thr (8 waves 4Mx2N, 64x64 each), triple-buffered LDS,
// 2 phases/K-tile (16 MFMA each), counted vmcnt(6) once per tile,
// both-sides XOR swizzle, setprio around MFMA clusters.
__global__ __launch_bounds__(512, 2) void k_gemm(
    const ushort_t* __restrict__ A,
    const ushort_t* __restrict__ Bt,
    const float* __restrict__ bias,
    float* __restrict__ C)
{
  __shared__ ushort_t lA[3][BM * BK];   // 3 x 32KB
  __shared__ ushort_t lB[3][BN * BK];   // 3 x 16KB  (total 144KB)

  const int tid  = threadIdx.x;
  const int lane = tid & 63;
  const int wid  = tid >> 6;     // 0..7
  const int wm   = wid >> 1;     // 0..3  (M quadrant, 64 rows)
  const int wn   = wid & 1;      // 0..1  (N half, 64 cols)
  const int fr   = lane & 15;
  const int fg   = lane >> 4;    // 0..3

  // XCD swizzle: 256 wgs; bm = bid&7 -> each XCD owns one A-panel (2MB, L2-fit)
  const int bid = blockIdx.x;
  const int bm  = bid & 7;       // 0..7
  const int bn  = bid >> 3;      // 0..31

  // ---- staging (linear LDS dest + inverse-swizzled global source) ----
  const int srow = tid >> 3;                               // 0..63
  const int scol = ((tid & 7) ^ (srow & 7)) << 3;          // swizzled source col (elems)
  const ushort_t* aSt = A  + (size_t)(bm * BM + srow) * K_DIM + scol;
  const ushort_t* bSt = Bt + (size_t)(bn * BN + srow) * K_DIM + scol;
  const int dE = tid * 8;                                  // linear dest (elems)

#define STAGE_A(kt, s, r_) async16(&lA[s][(r_) * 4096 + dE], \
                                   aSt + (size_t)(kt) * BK + (size_t)(r_) * 64 * K_DIM)
#define STAGE_B(kt, s, r_) async16(&lB[s][(r_) * 4096 + dE], \
                                   bSt + (size_t)(kt) * BK + (size_t)(r_) * 64 * K_DIM)

  // ---- fragment read addressing (swizzle applied on read) ----
  const int arowb = wm * 64 + fr;                // + m*16
  const int browb = wn * 64 + fr;                // + n*16
  const int c0 = ( fg      ^ (fr & 7)) << 3;     // kk=0 col (elems)
  const int c1 = ((fg + 4) ^ (fr & 7)) << 3;     // kk=1

  f32x4 acc[4][4];
  #pragma unroll
  for (int m = 0; m < 4; ++m)
    #pragma unroll
    for (int n = 0; n < 4; ++n)
      acc[m][n] = (f32x4){0.f, 0.f, 0.f, 0.f};

  // prologue: stage tiles 0,1 (6 chunks each)
  #pragma unroll
  for (int r_ = 0; r_ < 4; ++r_) STAGE_A(0, 0, r_);
  #pragma unroll
  for (int r_ = 0; r_ < 2; ++r_) STAGE_B(0, 0, r_);
  #pragma unroll
  for (int r_ = 0; r_ < 4; ++r_) STAGE_A(1, 1, r_);
  #pragma unroll
  for (int r_ = 0; r_ < 2; ++r_) STAGE_B(1, 1, r_);

  asm volatile("s_waitcnt vmcnt(6)" ::: "memory");   // tile 0 resident (per-wave)
  __builtin_amdgcn_s_barrier();                      // ... for ALL waves

  int sc = 0, ss = 2;
  for (int t = 0; t < NT; ++t) {
    const bool pre = (t + 2 < NT);
    const ushort_t* pA = &lA[sc][0];
    const ushort_t* pB = &lB[sc][0];

    // ================= phase 0: kk=0 (16 MFMA) =================
    {
      bf16x8 af[4], bf[4];
      #pragma unroll
      for (int m = 0; m < 4; ++m) af[m] = *(const bf16x8*)(pA + (arowb + m * 16) * 64 + c0);
      #pragma unroll
      for (int n = 0; n < 4; ++n) bf[n] = *(const bf16x8*)(pB + (browb + n * 16) * 64 + c0);
      if (pre) { STAGE_A(t + 2, ss, 0); STAGE_A(t + 2, ss, 1); STAGE_A(t + 2, ss, 2); }
      __builtin_amdgcn_s_barrier();
      __builtin_amdgcn_s_setprio(1);
      #pragma unroll
      for (int m = 0; m < 4; ++m)
        #pragma unroll
        for (int n = 0; n < 4; ++n)
          acc[m][n] = MFMA16(af[m], bf[n], acc[m][n]);
      __builtin_amdgcn_s_setprio(0);
      __builtin_amdgcn_s_barrier();
    }

    // ================= phase 1: kk=1 (16 MFMA) =================
    {
      bf16x8 af[4], bf[4];
      #pragma unroll
      for (int m = 0; m < 4; ++m) af[m] = *(const bf16x8*)(pA + (arowb + m * 16) * 64 + c1);
      #pragma unroll
      for (int n = 0; n < 4; ++n) bf[n] = *(const bf16x8*)(pB + (browb + n * 16) * 64 + c1);
      if (pre) { STAGE_A(t + 2, ss, 3); STAGE_B(t + 2, ss, 0); STAGE_B(t + 2, ss, 1); }
      __builtin_amdgcn_s_barrier();
      __builtin_amdgcn_s_setprio(1);
      #pragma unroll
      for (int m = 0; m < 4; ++m)
        #pragma unroll
        for (int n = 0; n < 4; ++n)
          acc[m][n] = MFMA16(af[m], bf[n], acc[m][n]);
      __builtin_amdgcn_s_setprio(0);
      if (t + 2 < NT)      asm volatile("s_waitcnt vmcnt(6)" ::: "memory");
      else if (t + 1 < NT) asm volatile("s_waitcnt vmcnt(0)" ::: "memory");
      __builtin_amdgcn_s_barrier();
    }

    sc = (sc == 2) ? 0 : sc + 1;
    ss = (ss == 2) ? 0 : ss + 1;
  }
#undef STAGE_A
#undef STAGE_B

  // epilogue: C/D layout col = lane&15, row = (lane>>4)*4 + reg
  const size_t row0 = (size_t)bm * BM + wm * 64;
  const int col0 = bn * BN + wn * 64;
  #pragma unroll
  for (int n = 0; n < 4; ++n) {
    const int col = col0 + n * 16 + fr;
    const float bv = bias[col];
    #pragma unroll
    for (int m = 0; m < 4; ++m) {
      const size_t r0 = row0 + m * 16 + fg * 4;
      #pragma unroll
      for (int r = 0; r < 4; ++r)
        C[(r0 + r) * N_DIM + col] = acc[m][n][r] + bv;
    }
  }
}

// ---------- launch ----------
extern "C" void kernel_launch(void* const* d_in, const int* in_sizes, int n_in,
                              void* d_out, int out_size, void* d_ws, size_t ws_size,
                              hipStream_t stream) {
  const float* x    = (const float*)d_in[0];
  const float* c0   = (const float*)d_in[1];
  const float* c1   = (const float*)d_in[2];
  const float* c2   = (const float*)d_in[3];
  const float* bias = (const float*)d_in[4];
  float* out = (float*)d_out;

  // workspace layout: Abf 16MB | Wt 32MB => 48MB needed
  const size_t NEED = (size_t)48 * 1024 * 1024;
  if (ws_size < NEED) return;

  char* ws = (char*)d_ws;
  ushort_t* Abf = (ushort_t*)ws;
  ushort_t* Wt  = (ushort_t*)(ws + (size_t)16 * 1024 * 1024);

  k_prep <<<6144, 256, 0, stream>>>(x, Abf, c0, c1, c2, Wt);
  k_gemm <<<256, 512, 0, stream>>>(Abf, Wt, bias, out);
}